// Round 5
// baseline (69.867 us; speedup 1.0000x reference)
//
#include <hip/hip_runtime.h>
#include <stdint.h>

#define D_M   1024
#define L_OBS 2048
#define ALPHA 8192
#define D_H   2048

typedef __attribute__((ext_vector_type(8))) short short8;
typedef __attribute__((ext_vector_type(4))) float f32x4;

__device__ inline unsigned short f2bf(float f) {
  union { float f; unsigned u; } c; c.f = f;
  unsigned u = c.u;
  u += 0x7fffu + ((u >> 16) & 1u);   // round-to-nearest-even
  return (unsigned short)(u >> 16);
}

// ---------------- Kernel 1: scatter + forward-fill, one row per block --------
__global__ __launch_bounds__(1024) void impute_fill(
    const float* __restrict__ x_ts, const int* __restrict__ t_ts,
    const float* __restrict__ gmean, unsigned short* __restrict__ dst,
    int transposed_out) {
  __shared__ unsigned long long pack[ALPHA];   // 64 KB; 0 = no observation
  __shared__ float s_wv[16];
  __shared__ int   s_wh[16];

  const int m    = blockIdx.x;
  const int tid  = threadIdx.x;
  const int lane = tid & 63;
  const int wv   = tid >> 6;

  #pragma unroll
  for (int i = 0; i < 8; ++i) pack[tid + i * 1024] = 0ull;
  __syncthreads();

  #pragma unroll
  for (int j = 0; j < 2; ++j) {
    const int l = tid + j * 1024;
    const float xv = x_ts[(size_t)m * L_OBS + l];
    const int   tv = t_ts[(size_t)m * L_OBS + l];
    if ((xv == xv) && (tv >= 0) && (tv < ALPHA)) {
      union { float f; unsigned u; } c; c.f = xv;
      atomicMax(&pack[tv], ((unsigned long long)(l + 1) << 32) | c.u);
    }
  }
  __syncthreads();

  const int base = tid * 8;
  int has = 0; float lv = 0.f;
  #pragma unroll
  for (int i = 0; i < 8; ++i) {
    const unsigned long long p = pack[base + i];
    if (p >> 32) { has = 1; lv = __uint_as_float((unsigned)p); }
  }

  int ihas = has; float ilv = lv;
  #pragma unroll
  for (int d = 1; d < 64; d <<= 1) {
    const float pv = __shfl_up(ilv, d, 64);
    const int   ph = __shfl_up(ihas, d, 64);
    if (lane >= d && !ihas) { ihas = ph; ilv = pv; }
  }
  if (lane == 63) { s_wh[wv] = ihas; s_wv[wv] = ilv; }
  __syncthreads();
  if (wv == 0 && lane < 16) {
    int h2 = s_wh[lane]; float v2 = s_wv[lane];
    #pragma unroll
    for (int d = 1; d < 16; d <<= 1) {
      const float pv = __shfl_up(v2, d, 16);
      const int   ph = __shfl_up(h2, d, 16);
      if (lane >= d && !h2) { h2 = ph; v2 = pv; }
    }
    s_wh[lane] = h2; s_wv[lane] = v2;
  }
  __syncthreads();

  const float xlv = __shfl_up(ilv, 1, 64);
  const int   xh_ = __shfl_up(ihas, 1, 64);
  const int   xhas = (lane > 0) ? xh_ : 0;
  float running;
  if (xhas)                         running = xlv;
  else if (wv > 0 && s_wh[wv - 1])  running = s_wv[wv - 1];
  else                              running = gmean[m];

  if (transposed_out) {
    #pragma unroll
    for (int i = 0; i < 8; ++i) {
      const unsigned long long p = pack[base + i];
      if (p >> 32) running = __uint_as_float((unsigned)p);
      dst[(size_t)(base + i) * D_M + m] = f2bf(running);
    }
  } else {
    short8 ov;
    #pragma unroll
    for (int i = 0; i < 8; ++i) {
      const unsigned long long p = pack[base + i];
      if (p >> 32) running = __uint_as_float((unsigned)p);
      ov[i] = (short)f2bf(running);
    }
    *(short8*)&dst[(size_t)m * ALPHA + base] = ov;
  }
}

// ---------------- Kernel 1b: transpose reg[m][a] -> regT[a][m] ---------------
__global__ __launch_bounds__(256) void transpose_bf(
    const unsigned short* __restrict__ reg, unsigned short* __restrict__ regT) {
  __shared__ unsigned short tile[64 * 64];
  const int t  = threadIdx.x;
  const int m0 = (blockIdx.x & 15) * 64;
  const int A0 = (blockIdx.x >> 4) * 64;

  #pragma unroll
  for (int i = 0; i < 2; ++i) {
    const int m  = i * 32 + (t >> 3);
    const int ao = (t & 7) * 8;
    short8 v = *(const short8*)&reg[(size_t)(m0 + m) * ALPHA + A0 + ao];
    const int s = ((m & 7) ^ (m >> 3)) << 3;
    *(short8*)&tile[m * 64 + (ao ^ s)] = v;
  }
  __syncthreads();
  #pragma unroll
  for (int i = 0; i < 2; ++i) {
    const int a  = i * 32 + (t >> 3);
    const int mo = (t & 7) * 8;
    short8 ov;
    #pragma unroll
    for (int j = 0; j < 8; ++j) {
      const int mm = mo + j;
      const int s  = ((mm & 7) ^ (mm >> 3)) << 3;
      ov[j] = (short)tile[mm * 64 + (a ^ s)];
    }
    *(short8*)&regT[(size_t)(A0 + a) * D_M + m0 + mo] = ov;
  }
}

// ---------------- Kernel 2: W f32 -> bf16 ------------------------------------
__global__ __launch_bounds__(256) void wconv(const float* __restrict__ W,
                                             unsigned short* __restrict__ Wb) {
  const int i = (blockIdx.x * 256 + threadIdx.x) * 4;
  const float4 w = *reinterpret_cast<const float4*>(&W[i]);
  ushort4 o;
  o.x = f2bf(w.x); o.y = f2bf(w.y); o.z = f2bf(w.z); o.w = f2bf(w.w);
  *reinterpret_cast<ushort4*>(&Wb[i]) = o;
}

// ---------------- Kernel 3: 256x256 GEMM, 8-phase template (m201 port) -------
// out[a][h] = sum_m regT[a][m] * Wb[h][m] + b[h];  M=8192 N=2048 K=1024.
// BK=64 -> 16 K-tiles; 4 phases/tile, 16 MFMA each (phase = k-half x n-pair).
// LDS: per-operand ring of 4 k-half slots (256 rows x 32k x 2B = 16KB):
//   A @ (kh&3)*16KB, B @ 64KB + (kh&3)*16KB.  Total 128 KB.
// Swizzle: 16B chunk s at row r holds logical chunk s^(r&3) (4 chunks/row)
//   -> wave reads spread over all 32 banks; applied inverse on global src.
// Stage 1 half/phase: ph1:B[2t+3] ph2:A[2t+4] ph3:B[2t+4] ph4:A[2t+5];
// every slot's ds_reads drain at lgkmcnt(0) >=1 phase before its re-stage.
// One vmcnt(6)/tile at ph4 (3 halves = 6 loads in flight; m218 counted-vmcnt).
#define GNT 16

__device__ inline void gload_lds16(const void* g, void* l) {
  __builtin_amdgcn_global_load_lds(
      (const __attribute__((address_space(1))) unsigned int*)g,
      (__attribute__((address_space(3))) unsigned int*)l, 16, 0, 0);
}

#define BARX() { asm volatile("" ::: "memory"); __builtin_amdgcn_s_barrier(); \
                 asm volatile("" ::: "memory"); }

__global__ __launch_bounds__(512, 2) void gemm_bias(
    const unsigned short* __restrict__ A,   // regT [ALPHA][D_M]
    const unsigned short* __restrict__ B,   // Wb   [D_H][D_M]
    const float* __restrict__ bias, float* __restrict__ out) {
  __shared__ char lds[131072];

  const int tid  = threadIdx.x;
  const int lane = tid & 63;
  const int wid  = tid >> 6;
  const int wm   = wid >> 2;                // 0..1  (m-half of C)
  const int wn   = wid & 3;                 // 0..3  (n-quarter of C)
  const int bn   = blockIdx.x & 7;          // bid%8 = XCD -> B panel L2-local
  const int bm   = blockIdx.x >> 3;
  const int a0 = bm * 256, h0 = bn * 256;

  f32x4 acc[8][4] = {};
  short8 af[8], bf[2];

  // ---- staging: linear LDS dest (tid*16), inverse-swizzled global source
  const int r0 = tid >> 2, s0 = tid & 3;
  const int swzB = ((s0 ^ (r0 & 3)) * 16);
  const char* Asrc0 = (const char*)A + ((size_t)(a0 + r0) * D_M) * 2 + swzB;
  const char* Asrc1 = Asrc0 + (size_t)128 * D_M * 2;   // rows +128 (swz invariant)
  const char* Bsrc0 = (const char*)B + ((size_t)(h0 + r0) * D_M) * 2 + swzB;
  const char* Bsrc1 = Bsrc0 + (size_t)128 * D_M * 2;

#define STAGE_A(kh) { char* d_ = lds + ((kh) & 3) * 16384 + tid * 16; \
  gload_lds16(Asrc0 + (size_t)(kh) * 64, d_); \
  gload_lds16(Asrc1 + (size_t)(kh) * 64, d_ + 8192); }
#define STAGE_B(kh) { char* d_ = lds + 65536 + ((kh) & 3) * 16384 + tid * 16; \
  gload_lds16(Bsrc0 + (size_t)(kh) * 64, d_); \
  gload_lds16(Bsrc1 + (size_t)(kh) * 64, d_ + 8192); }

  // ---- fragment read offsets (same involutive swizzle)
  const int rl  = lane & 15;
  const int rsw = ((lane >> 4) ^ (lane & 3)) * 16;
  const int Aro = (wm * 128 + rl) * 64 + rsw;           // + mf*1024 + (kh&3)*16K
  const int Bro = 65536 + (wn * 64 + rl) * 64 + rsw;    // + nf*1024 + (kh&3)*16K

#define RD_A(kh) { _Pragma("unroll") \
  for (int mf = 0; mf < 8; ++mf) \
    af[mf] = *(const short8*)(lds + ((kh) & 3) * 16384 + Aro + mf * 1024); }
#define RD_B(kh, np) { \
  bf[0] = *(const short8*)(lds + ((kh) & 3) * 16384 + Bro + ((np) * 2 + 0) * 1024); \
  bf[1] = *(const short8*)(lds + ((kh) & 3) * 16384 + Bro + ((np) * 2 + 1) * 1024); }

#define PH_MFMA(NP) \
  BARX(); \
  asm volatile("s_waitcnt lgkmcnt(0)" ::: "memory"); \
  __builtin_amdgcn_sched_barrier(0); \
  __builtin_amdgcn_s_setprio(1); \
  _Pragma("unroll") \
  for (int mf = 0; mf < 8; ++mf) { \
    acc[mf][(NP)*2+0] = __builtin_amdgcn_mfma_f32_16x16x32_bf16(af[mf], bf[0], acc[mf][(NP)*2+0], 0, 0, 0); \
    acc[mf][(NP)*2+1] = __builtin_amdgcn_mfma_f32_16x16x32_bf16(af[mf], bf[1], acc[mf][(NP)*2+1], 0, 0, 0); \
  } \
  __builtin_amdgcn_s_setprio(0); \
  BARX();

  // ---- prologue: 7 half-tiles issued, oldest 4 landed (vmcnt 14->6)
  STAGE_A(0); STAGE_B(0); STAGE_A(1); STAGE_B(1); STAGE_A(2); STAGE_B(2); STAGE_A(3);
  asm volatile("s_waitcnt vmcnt(6)" ::: "memory");
  BARX();

  // ---- steady loop: tiles 0..13 (all stages in range: max kh = 2*13+5 = 31)
  for (int t = 0; t < GNT - 2; ++t) {
    const int kh0 = 2 * t, kh1 = 2 * t + 1;
    // ph1: k0, n01
    RD_A(kh0); RD_B(kh0, 0);
    STAGE_B(kh0 + 3);
    PH_MFMA(0);
    // ph2: k0, n23
    RD_B(kh0, 1);
    STAGE_A(kh0 + 4);
    PH_MFMA(1);
    // ph3: k1, n01
    RD_A(kh1); RD_B(kh1, 0);
    STAGE_B(kh0 + 4);
    PH_MFMA(0);
    // ph4: k1, n23
    RD_B(kh1, 1);
    STAGE_A(kh0 + 5);
    asm volatile("s_waitcnt vmcnt(6)" ::: "memory");
    PH_MFMA(1);
  }
  // ---- tail t=14: kh 28/29; only B[31] remains to stage
  {
    RD_A(28); RD_B(28, 0);
    STAGE_B(31);
    PH_MFMA(0);
    RD_B(28, 1);
    PH_MFMA(1);
    RD_A(29); RD_B(29, 0);
    PH_MFMA(0);
    RD_B(29, 1);
    asm volatile("s_waitcnt vmcnt(4)" ::: "memory");   // leave {A31,B31}
    PH_MFMA(1);
  }
  // ---- tail t=15: kh 30/31; drain remaining before ph3 reads
  {
    RD_A(30); RD_B(30, 0);
    PH_MFMA(0);
    RD_B(30, 1);
    asm volatile("s_waitcnt vmcnt(0)" ::: "memory");
    PH_MFMA(1);
    RD_A(31); RD_B(31, 0);
    PH_MFMA(0);
    RD_B(31, 1);
    PH_MFMA(1);
  }

  // ---- epilogue: C row = (lane>>4)*4 + r (A side), col = lane&15 (B side)
  const int cl = lane & 15, rq = lane >> 4;
  #pragma unroll
  for (int n = 0; n < 4; ++n) {
    const int h = h0 + wn * 64 + n * 16 + cl;
    const float bv = bias[h];
    #pragma unroll
    for (int f = 0; f < 8; ++f) {
      const int ar = a0 + wm * 128 + f * 16 + rq * 4;
      #pragma unroll
      for (int r = 0; r < 4; ++r)
        out[(size_t)(ar + r) * D_H + h] = acc[f][n][r] + bv;
    }
  }
#undef STAGE_A
#undef STAGE_B
#undef RD_A
#undef RD_B
#undef PH_MFMA
}

extern "C" void kernel_launch(void* const* d_in, const int* in_sizes, int n_in,
                              void* d_out, int out_size, void* d_ws, size_t ws_size,
                              hipStream_t stream) {
  const float* x  = (const float*)d_in[0];
  const int*   t  = (const int*)d_in[1];
  const float* gm = (const float*)d_in[2];
  const float* W  = (const float*)d_in[3];
  const float* b  = (const float*)d_in[4];
  float* out = (float*)d_out;

  const size_t SZ_REG = (size_t)ALPHA * D_M * 2;   // 16 MB
  const size_t SZ_WB  = (size_t)D_H * D_M * 2;     //  4 MB

  if (ws_size >= 2 * SZ_REG + SZ_WB) {
    unsigned short* reg  = (unsigned short*)d_ws;
    unsigned short* regT = (unsigned short*)((char*)d_ws + SZ_REG);
    unsigned short* Wb   = (unsigned short*)((char*)d_ws + 2 * SZ_REG);
    impute_fill<<<D_M, 1024, 0, stream>>>(x, t, gm, reg, 0);
    wconv<<<(D_H * D_M) / 1024, 256, 0, stream>>>(W, Wb);
    transpose_bf<<<(ALPHA / 64) * (D_M / 64), 256, 0, stream>>>(reg, regT);
    gemm_bias<<<(ALPHA / 256) * (D_H / 256), 512, 0, stream>>>(regT, Wb, b, out);
  } else {
    unsigned short* regT = (unsigned short*)d_ws;
    unsigned short* Wb   = (unsigned short*)((char*)d_ws + SZ_REG);
    impute_fill<<<D_M, 1024, 0, stream>>>(x, t, gm, regT, 1);
    wconv<<<(D_H * D_M) / 1024, 256, 0, stream>>>(W, Wb);
    gemm_bias<<<(ALPHA / 256) * (D_H / 256), 512, 0, stream>>>(regT, Wb, b, out);
  }
}

// Round 6
// 66.421 us; speedup vs baseline: 1.0519x; 1.0519x over previous
//
#include <hip/hip_runtime.h>
#include <stdint.h>

#define D_M   1024
#define L_OBS 2048
#define ALPHA 8192
#define D_H   2048

typedef __attribute__((ext_vector_type(8))) short short8;
typedef __attribute__((ext_vector_type(4))) float f32x4;

__device__ inline unsigned short f2bf(float f) {
  union { float f; unsigned u; } c; c.f = f;
  unsigned u = c.u;
  u += 0x7fffu + ((u >> 16) & 1u);   // round-to-nearest-even
  return (unsigned short)(u >> 16);
}

// ---------------- Kernel 1: scatter + forward-fill, one row per block --------
__global__ __launch_bounds__(1024) void impute_fill(
    const float* __restrict__ x_ts, const int* __restrict__ t_ts,
    const float* __restrict__ gmean, unsigned short* __restrict__ dst,
    int transposed_out) {
  __shared__ unsigned long long pack[ALPHA];   // 64 KB; 0 = no observation
  __shared__ float s_wv[16];
  __shared__ int   s_wh[16];

  const int m    = blockIdx.x;
  const int tid  = threadIdx.x;
  const int lane = tid & 63;
  const int wv   = tid >> 6;

  #pragma unroll
  for (int i = 0; i < 8; ++i) pack[tid + i * 1024] = 0ull;
  __syncthreads();

  #pragma unroll
  for (int j = 0; j < 2; ++j) {
    const int l = tid + j * 1024;
    const float xv = x_ts[(size_t)m * L_OBS + l];
    const int   tv = t_ts[(size_t)m * L_OBS + l];
    if ((xv == xv) && (tv >= 0) && (tv < ALPHA)) {
      union { float f; unsigned u; } c; c.f = xv;
      atomicMax(&pack[tv], ((unsigned long long)(l + 1) << 32) | c.u);
    }
  }
  __syncthreads();

  const int base = tid * 8;
  int has = 0; float lv = 0.f;
  #pragma unroll
  for (int i = 0; i < 8; ++i) {
    const unsigned long long p = pack[base + i];
    if (p >> 32) { has = 1; lv = __uint_as_float((unsigned)p); }
  }

  int ihas = has; float ilv = lv;
  #pragma unroll
  for (int d = 1; d < 64; d <<= 1) {
    const float pv = __shfl_up(ilv, d, 64);
    const int   ph = __shfl_up(ihas, d, 64);
    if (lane >= d && !ihas) { ihas = ph; ilv = pv; }
  }
  if (lane == 63) { s_wh[wv] = ihas; s_wv[wv] = ilv; }
  __syncthreads();
  if (wv == 0 && lane < 16) {
    int h2 = s_wh[lane]; float v2 = s_wv[lane];
    #pragma unroll
    for (int d = 1; d < 16; d <<= 1) {
      const float pv = __shfl_up(v2, d, 16);
      const int   ph = __shfl_up(h2, d, 16);
      if (lane >= d && !h2) { h2 = ph; v2 = pv; }
    }
    s_wh[lane] = h2; s_wv[lane] = v2;
  }
  __syncthreads();

  const float xlv = __shfl_up(ilv, 1, 64);
  const int   xh_ = __shfl_up(ihas, 1, 64);
  const int   xhas = (lane > 0) ? xh_ : 0;
  float running;
  if (xhas)                         running = xlv;
  else if (wv > 0 && s_wh[wv - 1])  running = s_wv[wv - 1];
  else                              running = gmean[m];

  if (transposed_out) {
    #pragma unroll
    for (int i = 0; i < 8; ++i) {
      const unsigned long long p = pack[base + i];
      if (p >> 32) running = __uint_as_float((unsigned)p);
      dst[(size_t)(base + i) * D_M + m] = f2bf(running);
    }
  } else {
    short8 ov;
    #pragma unroll
    for (int i = 0; i < 8; ++i) {
      const unsigned long long p = pack[base + i];
      if (p >> 32) running = __uint_as_float((unsigned)p);
      ov[i] = (short)f2bf(running);
    }
    *(short8*)&dst[(size_t)m * ALPHA + base] = ov;
  }
}

// ---------------- Kernel 1b: transpose reg[m][a] -> regT[a][m] ---------------
__global__ __launch_bounds__(256) void transpose_bf(
    const unsigned short* __restrict__ reg, unsigned short* __restrict__ regT) {
  __shared__ unsigned short tile[64 * 64];
  const int t  = threadIdx.x;
  const int m0 = (blockIdx.x & 15) * 64;
  const int A0 = (blockIdx.x >> 4) * 64;

  #pragma unroll
  for (int i = 0; i < 2; ++i) {
    const int m  = i * 32 + (t >> 3);
    const int ao = (t & 7) * 8;
    short8 v = *(const short8*)&reg[(size_t)(m0 + m) * ALPHA + A0 + ao];
    const int s = ((m & 7) ^ (m >> 3)) << 3;
    *(short8*)&tile[m * 64 + (ao ^ s)] = v;
  }
  __syncthreads();
  #pragma unroll
  for (int i = 0; i < 2; ++i) {
    const int a  = i * 32 + (t >> 3);
    const int mo = (t & 7) * 8;
    short8 ov;
    #pragma unroll
    for (int j = 0; j < 8; ++j) {
      const int mm = mo + j;
      const int s  = ((mm & 7) ^ (mm >> 3)) << 3;
      ov[j] = (short)tile[mm * 64 + (a ^ s)];
    }
    *(short8*)&regT[(size_t)(A0 + a) * D_M + m0 + mo] = ov;
  }
}

// ---------------- Kernel 2: W f32 -> bf16 ------------------------------------
__global__ __launch_bounds__(256) void wconv(const float* __restrict__ W,
                                             unsigned short* __restrict__ Wb) {
  const int i = (blockIdx.x * 256 + threadIdx.x) * 4;
  const float4 w = *reinterpret_cast<const float4*>(&W[i]);
  ushort4 o;
  o.x = f2bf(w.x); o.y = f2bf(w.y); o.z = f2bf(w.z); o.w = f2bf(w.w);
  *reinterpret_cast<ushort4*>(&Wb[i]) = o;
}

// ---------------- Kernel 3: 256x256 GEMM, 8-phase template ------------------
// Identical to R5 except the swizzle pair reverted to R4's 0-conflict form:
//   staging source chunk = s0 ^ ((r0>>1)&3); read chunk = kb ^ ((rl>>1)&3).
// R5's (lane&3)-based pair caused a 4-way ds_read bank conflict (3.1M/disp).
#define GNT 16

__device__ inline void gload_lds16(const void* g, void* l) {
  __builtin_amdgcn_global_load_lds(
      (const __attribute__((address_space(1))) unsigned int*)g,
      (__attribute__((address_space(3))) unsigned int*)l, 16, 0, 0);
}

#define BARX() { asm volatile("" ::: "memory"); __builtin_amdgcn_s_barrier(); \
                 asm volatile("" ::: "memory"); }

__global__ __launch_bounds__(512, 2) void gemm_bias(
    const unsigned short* __restrict__ A,   // regT [ALPHA][D_M]
    const unsigned short* __restrict__ B,   // Wb   [D_H][D_M]
    const float* __restrict__ bias, float* __restrict__ out) {
  __shared__ char lds[131072];

  const int tid  = threadIdx.x;
  const int lane = tid & 63;
  const int wid  = tid >> 6;
  const int wm   = wid >> 2;                // 0..1  (m-half of C)
  const int wn   = wid & 3;                 // 0..3  (n-quarter of C)
  const int bn   = blockIdx.x & 7;          // bid%8 = XCD -> B panel L2-local
  const int bm   = blockIdx.x >> 3;
  const int a0 = bm * 256, h0 = bn * 256;

  f32x4 acc[8][4] = {};
  short8 af[8], bf[2];

  // ---- staging: linear LDS dest (tid*16), inverse-swizzled global source
  const int r0 = tid >> 2, s0 = tid & 3;
  const int swzB = (s0 ^ ((r0 >> 1) & 3)) * 16;        // R4 form: 0 conflicts
  const char* Asrc0 = (const char*)A + ((size_t)(a0 + r0) * D_M) * 2 + swzB;
  const char* Asrc1 = Asrc0 + (size_t)128 * D_M * 2;   // rows +128 (swz invariant)
  const char* Bsrc0 = (const char*)B + ((size_t)(h0 + r0) * D_M) * 2 + swzB;
  const char* Bsrc1 = Bsrc0 + (size_t)128 * D_M * 2;

#define STAGE_A(kh) { char* d_ = lds + ((kh) & 3) * 16384 + tid * 16; \
  gload_lds16(Asrc0 + (size_t)(kh) * 64, d_); \
  gload_lds16(Asrc1 + (size_t)(kh) * 64, d_ + 8192); }
#define STAGE_B(kh) { char* d_ = lds + 65536 + ((kh) & 3) * 16384 + tid * 16; \
  gload_lds16(Bsrc0 + (size_t)(kh) * 64, d_); \
  gload_lds16(Bsrc1 + (size_t)(kh) * 64, d_ + 8192); }

  // ---- fragment read offsets (same involutive swizzle, R4 form)
  const int rl  = lane & 15;
  const int rsw = (((lane >> 4) ^ ((rl >> 1) & 3))) * 16;
  const int Aro = (wm * 128 + rl) * 64 + rsw;           // + mf*1024 + (kh&3)*16K
  const int Bro = 65536 + (wn * 64 + rl) * 64 + rsw;    // + nf*1024 + (kh&3)*16K

#define RD_A(kh) { _Pragma("unroll") \
  for (int mf = 0; mf < 8; ++mf) \
    af[mf] = *(const short8*)(lds + ((kh) & 3) * 16384 + Aro + mf * 1024); }
#define RD_B(kh, np) { \
  bf[0] = *(const short8*)(lds + ((kh) & 3) * 16384 + Bro + ((np) * 2 + 0) * 1024); \
  bf[1] = *(const short8*)(lds + ((kh) & 3) * 16384 + Bro + ((np) * 2 + 1) * 1024); }

#define PH_MFMA(NP) \
  BARX(); \
  asm volatile("s_waitcnt lgkmcnt(0)" ::: "memory"); \
  __builtin_amdgcn_sched_barrier(0); \
  __builtin_amdgcn_s_setprio(1); \
  _Pragma("unroll") \
  for (int mf = 0; mf < 8; ++mf) { \
    acc[mf][(NP)*2+0] = __builtin_amdgcn_mfma_f32_16x16x32_bf16(af[mf], bf[0], acc[mf][(NP)*2+0], 0, 0, 0); \
    acc[mf][(NP)*2+1] = __builtin_amdgcn_mfma_f32_16x16x32_bf16(af[mf], bf[1], acc[mf][(NP)*2+1], 0, 0, 0); \
  } \
  __builtin_amdgcn_s_setprio(0); \
  BARX();

  // ---- prologue: 7 half-tiles issued, oldest 4 landed (vmcnt 14->6)
  STAGE_A(0); STAGE_B(0); STAGE_A(1); STAGE_B(1); STAGE_A(2); STAGE_B(2); STAGE_A(3);
  asm volatile("s_waitcnt vmcnt(6)" ::: "memory");
  BARX();

  // ---- steady loop: tiles 0..13 (all stages in range: max kh = 2*13+5 = 31)
  for (int t = 0; t < GNT - 2; ++t) {
    const int kh0 = 2 * t, kh1 = 2 * t + 1;
    // ph1: k0, n01
    RD_A(kh0); RD_B(kh0, 0);
    STAGE_B(kh0 + 3);
    PH_MFMA(0);
    // ph2: k0, n23
    RD_B(kh0, 1);
    STAGE_A(kh0 + 4);
    PH_MFMA(1);
    // ph3: k1, n01
    RD_A(kh1); RD_B(kh1, 0);
    STAGE_B(kh0 + 4);
    PH_MFMA(0);
    // ph4: k1, n23
    RD_B(kh1, 1);
    STAGE_A(kh0 + 5);
    asm volatile("s_waitcnt vmcnt(6)" ::: "memory");
    PH_MFMA(1);
  }
  // ---- tail t=14: kh 28/29; only B[31] remains to stage
  {
    RD_A(28); RD_B(28, 0);
    STAGE_B(31);
    PH_MFMA(0);
    RD_B(28, 1);
    PH_MFMA(1);
    RD_A(29); RD_B(29, 0);
    PH_MFMA(0);
    RD_B(29, 1);
    asm volatile("s_waitcnt vmcnt(4)" ::: "memory");   // leave {A31,B31}
    PH_MFMA(1);
  }
  // ---- tail t=15: kh 30/31; drain remaining before ph3 reads
  {
    RD_A(30); RD_B(30, 0);
    PH_MFMA(0);
    RD_B(30, 1);
    asm volatile("s_waitcnt vmcnt(0)" ::: "memory");
    PH_MFMA(1);
    RD_A(31); RD_B(31, 0);
    PH_MFMA(0);
    RD_B(31, 1);
    PH_MFMA(1);
  }

  // ---- epilogue: C row = (lane>>4)*4 + r (A side), col = lane&15 (B side)
  const int cl = lane & 15, rq = lane >> 4;
  #pragma unroll
  for (int n = 0; n < 4; ++n) {
    const int h = h0 + wn * 64 + n * 16 + cl;
    const float bv = bias[h];
    #pragma unroll
    for (int f = 0; f < 8; ++f) {
      const int ar = a0 + wm * 128 + f * 16 + rq * 4;
      #pragma unroll
      for (int r = 0; r < 4; ++r)
        out[(size_t)(ar + r) * D_H + h] = acc[f][n][r] + bv;
    }
  }
#undef STAGE_A
#undef STAGE_B
#undef RD_A
#undef RD_B
#undef PH_MFMA
}

extern "C" void kernel_launch(void* const* d_in, const int* in_sizes, int n_in,
                              void* d_out, int out_size, void* d_ws, size_t ws_size,
                              hipStream_t stream) {
  const float* x  = (const float*)d_in[0];
  const int*   t  = (const int*)d_in[1];
  const float* gm = (const float*)d_in[2];
  const float* W  = (const float*)d_in[3];
  const float* b  = (const float*)d_in[4];
  float* out = (float*)d_out;

  const size_t SZ_REG = (size_t)ALPHA * D_M * 2;   // 16 MB
  const size_t SZ_WB  = (size_t)D_H * D_M * 2;     //  4 MB

  if (ws_size >= 2 * SZ_REG + SZ_WB) {
    unsigned short* reg  = (unsigned short*)d_ws;
    unsigned short* regT = (unsigned short*)((char*)d_ws + SZ_REG);
    unsigned short* Wb   = (unsigned short*)((char*)d_ws + 2 * SZ_REG);
    impute_fill<<<D_M, 1024, 0, stream>>>(x, t, gm, reg, 0);
    wconv<<<(D_H * D_M) / 1024, 256, 0, stream>>>(W, Wb);
    transpose_bf<<<(ALPHA / 64) * (D_M / 64), 256, 0, stream>>>(reg, regT);
    gemm_bias<<<(ALPHA / 256) * (D_H / 256), 512, 0, stream>>>(regT, Wb, b, out);
  } else {
    unsigned short* regT = (unsigned short*)d_ws;
    unsigned short* Wb   = (unsigned short*)((char*)d_ws + SZ_REG);
    impute_fill<<<D_M, 1024, 0, stream>>>(x, t, gm, regT, 1);
    wconv<<<(D_H * D_M) / 1024, 256, 0, stream>>>(W, Wb);
    gemm_bias<<<(ALPHA / 256) * (D_H / 256), 512, 0, stream>>>(regT, Wb, b, out);
  }
}